// Round 9
// baseline (53.884 us; speedup 1.0000x reference)
//
#include <hip/hip_runtime.h>
#include <hip/hip_bf16.h>

#define NN 16384
#define DD 64
#define NBI 32                 // 512-row bands
#define NUNITS 2112            // sum_I (128 - 4I), I=0..31
#define NBLK 512               // 2 blocks/CU
#define NPOSB (NN/4)
#define SCREEN_T 0.49f         // hinge>0 needs gram > ~0.5-3e-5; margin 1e-2

constexpr float F_EPS_PD   = 1e-6f;
constexpr float F_EPS_NORM = 1e-6f;

using bf16x8 = __attribute__((ext_vector_type(8))) short;
using f32x4  = __attribute__((ext_vector_type(4))) float;
typedef __attribute__((address_space(1))) const unsigned int gu32_t;
typedef __attribute__((address_space(3))) unsigned int       lu32_t;

__device__ __forceinline__ float wave_sum_f(float v) {
    #pragma unroll
    for (int o = 32; o >= 1; o >>= 1) v += __shfl_xor(v, o);
    return v;
}

// unit offset of band I (units are (band, col-tile) with tj in [4I,128))
__device__ __forceinline__ int band_off(int I) { return 2 * I * (65 - I); }

// ---------------------------------------------------------------------------
// Kernel 1: per-row normalize + bf16 copy + packed {u,lab}/{vc,lab} + exact
// fp32 positive-pair loss.   d2(i,j) = u_i + vc_j - 2*gram(i,j)
// ---------------------------------------------------------------------------
__global__ __launch_bounds__(256) void norm_kernel(
    const float* __restrict__ emb, const int* __restrict__ pidx,
    const int* __restrict__ lab, float2* __restrict__ up,
    float2* __restrict__ vcp, __hip_bfloat16* __restrict__ ebf,
    float* __restrict__ posP) {
    int w    = threadIdx.x >> 6;
    int row  = blockIdx.x * 4 + w;
    int lane = threadIdx.x & 63;
    int j    = pidx[row];
    float x  = emb[(size_t)row * DD + lane];
    float xj = emb[(size_t)j   * DD + lane];

    float n2  = wave_sum_f(x * x);
    float sx  = wave_sum_f(x);
    float n2j = wave_sum_f(xj * xj);
    float sxj = wave_sum_f(xj);
    float dot = wave_sum_f(x * xj);

    float m  = fmaxf(sqrtf(n2),  F_EPS_NORM);
    float mj = fmaxf(sqrtf(n2j), F_EPS_NORM);
    ebf[(size_t)row * DD + lane] = __float2bfloat16(x / m);

    __shared__ float spos[4];
    if (lane == 0) {
        float sq  = n2 / (m * m);
        float sqj = n2j / (mj * mj);
        float s   = sx / m;
        float sj  = sxj / mj;
        float g   = dot / (m * mj);
        float lf  = (float)lab[row];
        up[row]  = make_float2(sq + 2.0f * F_EPS_PD * s, lf);
        vcp[row] = make_float2(
            sq - 2.0f * F_EPS_PD * s + (float)DD * F_EPS_PD * F_EPS_PD, lf);
        float d2p = sq + sqj - 2.0f * g + 2.0f * F_EPS_PD * (s - sj)
                  + (float)DD * F_EPS_PD * F_EPS_PD;
        spos[w] = fmaxf(d2p, 0.0f);
    }
    __syncthreads();
    if (threadIdx.x == 0)
        posP[blockIdx.x] = spos[0] + spos[1] + spos[2] + spos[3];
}

// ---------------------------------------------------------------------------
// Stage one (B tile 16 KB + vcp slice 1 KB) into a ring slot. 3 ops per wave
// (uniform -> exact vmcnt counts). B source XOR-preswizzled (both-sides rule).
// ---------------------------------------------------------------------------
__device__ __forceinline__ void stage_tile(const short* ebf, const float2* vcp,
                                           int tile, short* slotB, float2* slotV,
                                           int w, int lane) {
    const short* tbase = ebf + (size_t)tile * (128 * DD);
    int rlo = lane >> 3;
    int g   = (lane & 7) ^ rlo;
    #pragma unroll
    for (int q = 0; q < 2; ++q) {
        int m = w * 2 + q;
        __builtin_amdgcn_global_load_lds(
            (gu32_t*)(const void*)(tbase + (size_t)(8 * m + rlo) * DD + g * 8),
            (lu32_t*)(void*)(slotB + m * 512), 16, 0, 0);
    }
    __builtin_amdgcn_global_load_lds(
        (gu32_t*)(const void*)(vcp + (size_t)tile * 128 + lane * 2),
        (lu32_t*)(void*)slotV, 16, 0, 0);
}

// ---------------------------------------------------------------------------
// Kernel 2: 8-wave blocks over (512-row band I, 128-col tile tj), tj>=4I.
// Counted-vmcnt ring (3 slots, 2-deep prefetch), zero vmem in compute.
// NEW (R9): accumulator double-buffer cA/cB — the screen of step t runs
// AFTER the MFMA burst of step t+1, so VALU reads of MFMA-dest registers
// happen ~120+ cy after the write (clears the MFMA->VALU RAW interlock that
// barrier-synced waves otherwise hit simultaneously). s_setprio(1) wraps
// each MFMA burst (T5: loop now has phase diversity).
// ---------------------------------------------------------------------------
#define MFMA_STEP(CD, t_)                                                      \
    do {                                                                       \
        const short* rowp_ = lb + ((t_) * 16 + lrow) * 64;                     \
        bf16x8 b0_ = *(const bf16x8*)(rowp_ + c0s);                            \
        bf16x8 b1_ = *(const bf16x8*)(rowp_ + c1s);                            \
        __builtin_amdgcn_s_setprio(1);                                         \
        _Pragma("unroll")                                                      \
        for (int s_ = 0; s_ < 4; ++s_) {                                       \
            f32x4 z_ = {0.f, 0.f, 0.f, 0.f};                                   \
            z_ = __builtin_amdgcn_mfma_f32_16x16x32_bf16(a[s_][0], b0_, z_, 0, 0, 0); \
            z_ = __builtin_amdgcn_mfma_f32_16x16x32_bf16(a[s_][1], b1_, z_, 0, 0, 0); \
            CD[s_] = z_;                                                       \
        }                                                                      \
        __builtin_amdgcn_s_setprio(0);                                         \
    } while (0)

#define SCREEN_STEP(CS, t_)                                                    \
    do {                                                                       \
        float mx_ = fmaxf(fmaxf(CS[0][0], CS[0][1]), fmaxf(CS[0][2], CS[0][3])); \
        mx_ = fmaxf(mx_, fmaxf(fmaxf(CS[1][0], CS[1][1]), fmaxf(CS[1][2], CS[1][3]))); \
        mx_ = fmaxf(mx_, fmaxf(fmaxf(CS[2][0], CS[2][1]), fmaxf(CS[2][2], CS[2][3]))); \
        mx_ = fmaxf(mx_, fmaxf(fmaxf(CS[3][0], CS[3][1]), fmaxf(CS[3][2], CS[3][3]))); \
        if (__any(mx_ > SCREEN_T)) {                                           \
            float2 vl_ = lv[(t_) * 16 + lrow];                                 \
            _Pragma("unroll")                                                  \
            for (int s_ = 0; s_ < 4; ++s_) {                                   \
                _Pragma("unroll")                                              \
                for (int r_ = 0; r_ < 4; ++r_) {                               \
                    float2 ul_ = uband[w * 64 + 16 * s_ + lkh * 4 + r_];       \
                    float d2_ = fmaf(-2.0f, CS[s_][r_], ul_.x + vl_.x);        \
                    float d_  = sqrtf(fmaxf(d2_, 1e-12f));                     \
                    float h_  = fmaxf(1.0f - d_, 0.0f);                        \
                    if (ul_.y != vl_.y) hp = fmaf(h_, h_, hp);                 \
                }                                                              \
            }                                                                  \
        }                                                                      \
    } while (0)

__global__ __launch_bounds__(512, 4) void pair_kernel(
    const short* __restrict__ ebf, const float2* __restrict__ up,
    const float2* __restrict__ vcp, float* __restrict__ negP) {
    __shared__ short  ringB[3][8192];   // 3 x 16 KB B tiles (swizzled)
    __shared__ float2 ringV[3][128];    // 3 x 1 KB {vc,lab} slices
    __shared__ float2 uband[512];       // band {u,lab}, staged per segment
    __shared__ float  sred[8];
    int tid  = threadIdx.x;
    int w    = tid >> 6;
    int lane = tid & 63;
    int lrow = lane & 15, lkh = lane >> 4;
    int c0s  = ((lkh)     ^ (lrow & 7)) * 8;   // swizzled K[0:32) chunk
    int c1s  = ((lkh + 4) ^ (lrow & 7)) * 8;   // swizzled K[32:64) chunk

    int ks = (int)(((long long)blockIdx.x * NUNITS) / NBLK);
    int ke = (int)(((long long)(blockIdx.x + 1) * NUNITS) / NBLK);

    // decode ks -> band I
    int I = (int)((65.0f - sqrtf(4225.0f - 2.0f * (float)ks)) * 0.5f);
    I = I < 0 ? 0 : (I > NBI - 1 ? NBI - 1 : I);
    while (band_off(I) > ks) --I;
    while (I < NBI - 1 && band_off(I + 1) <= ks) ++I;

    float hacc = 0.0f;
    int u0 = ks;
    while (u0 < ke) {
        int bend = band_off(I + 1);
        int n    = (ke < bend ? ke : bend) - u0;
        int tj0  = 4 * I + (u0 - band_off(I));
        int rowbase = I * 512 + w * 64;
        int rt      = 4 * I + (w >> 1);

        // --- segment prologue: A frags, u-band stage, prime 2 tiles ---
        bf16x8 a[4][2];
        #pragma unroll
        for (int s = 0; s < 4; ++s) {
            const short* ab = ebf + (size_t)(rowbase + 16 * s + lrow) * DD + lkh * 8;
            a[s][0] = *(const bf16x8*)(ab);
            a[s][1] = *(const bf16x8*)(ab + 32);
        }
        if (w < 4)
            __builtin_amdgcn_global_load_lds(
                (gu32_t*)(const void*)(up + (size_t)I * 512 + w * 128 + lane * 2),
                (lu32_t*)(void*)(uband + w * 128), 16, 0, 0);
        stage_tile(ebf, vcp, tj0, &ringB[0][0], &ringV[0][0], w, lane);
        if (n > 1)
            stage_tile(ebf, vcp, tj0 + 1, &ringB[1][0], &ringV[1][0], w, lane);

        int sl = 0;                        // ring slot of tile k
        for (int k = 0; k < n; ++k) {
            if (k + 1 < n) asm volatile("s_waitcnt vmcnt(3)" ::: "memory");
            else           asm volatile("s_waitcnt vmcnt(0)" ::: "memory");
            __builtin_amdgcn_s_barrier();
            __builtin_amdgcn_sched_barrier(0);
            int sl2 = (sl >= 1) ? sl - 1 : 2;     // slot of tile k+2
            if (k + 2 < n)
                stage_tile(ebf, vcp, tj0 + k + 2, &ringB[sl2][0], &ringV[sl2][0],
                           w, lane);

            int tj = tj0 + k;
            float wgt = (tj == rt) ? 1.0f : ((tj > rt) ? 2.0f : 0.0f);
            if (wgt != 0.0f) {
                const short*  lb = &ringB[sl][0];
                const float2* lv = &ringV[sl][0];
                float hp = 0.0f;
                f32x4 cA[4], cB[4];
                MFMA_STEP(cA, 0);
                MFMA_STEP(cB, 1);
                SCREEN_STEP(cA, 0);
                MFMA_STEP(cA, 2);
                SCREEN_STEP(cB, 1);
                MFMA_STEP(cB, 3);
                SCREEN_STEP(cA, 2);
                MFMA_STEP(cA, 4);
                SCREEN_STEP(cB, 3);
                MFMA_STEP(cB, 5);
                SCREEN_STEP(cA, 4);
                MFMA_STEP(cA, 6);
                SCREEN_STEP(cB, 5);
                MFMA_STEP(cB, 7);
                SCREEN_STEP(cA, 6);
                SCREEN_STEP(cB, 7);
                hacc = fmaf(wgt, hp, hacc);
            }
            sl = (sl + 1 == 3) ? 0 : sl + 1;
        }
        __builtin_amdgcn_s_barrier();      // protect ring/uband reuse
        __builtin_amdgcn_sched_barrier(0);
        u0 += n;
        ++I;
    }

    hacc = wave_sum_f(hacc);
    if (lane == 0) sred[w] = hacc;
    __syncthreads();
    if (tid == 0) {
        float tn = 0.f;
        #pragma unroll
        for (int i = 0; i < 8; ++i) tn += sred[i];
        negP[blockIdx.x] = tn;
    }
}

// ---------------------------------------------------------------------------
// Kernel 3: final reduction + 4-replica label histogram -> analytic negative
// count: n_neg = N^2 - sum_c n_c^2 ; n_comparisons = N + n_neg
// ---------------------------------------------------------------------------
__global__ __launch_bounds__(1024) void reduce_kernel(
    const float* __restrict__ posP, const float* __restrict__ negP,
    const int* __restrict__ lab, float* __restrict__ out) {
    __shared__ unsigned int hist[4][1024];
    int t = threadIdx.x;
    int w = t >> 6, lane = t & 63;
    for (int i = t; i < 4096; i += 1024) hist[i >> 10][i & 1023] = 0u;
    __syncthreads();
    const int4* lab4 = (const int4*)lab;
    for (int i = t; i < NN / 4; i += 1024) {
        int4 v = lab4[i];
        atomicAdd(&hist[w & 3][v.x & 1023], 1u);
        atomicAdd(&hist[w & 3][v.y & 1023], 1u);
        atomicAdd(&hist[w & 3][v.z & 1023], 1u);
        atomicAdd(&hist[w & 3][v.w & 1023], 1u);
    }
    __syncthreads();

    float ps = 0.f, ns = 0.f;
    unsigned long long sqc = 0u;
    const float4* posP4 = (const float4*)posP;
    for (int i = t; i < NPOSB / 4; i += 1024) {
        float4 v = posP4[i];
        ps += (v.x + v.y) + (v.z + v.w);
    }
    if (t < NBLK) ns = negP[t];
    for (int i = t; i < 1024; i += 1024) {
        unsigned long long h = (unsigned long long)hist[0][i] + hist[1][i]
                             + hist[2][i] + hist[3][i];
        sqc += h * h;
    }

    ps = wave_sum_f(ps);
    ns = wave_sum_f(ns);
    #pragma unroll
    for (int o = 32; o >= 1; o >>= 1) sqc += __shfl_xor(sqc, o);

    __shared__ float sp[16], sn[16];
    __shared__ unsigned long long sc[16];
    if (lane == 0) { sp[w] = ps; sn[w] = ns; sc[w] = sqc; }
    __syncthreads();
    if (t == 0) {
        float pos = 0.f, neg = 0.f;
        unsigned long long s2 = 0;
        #pragma unroll
        for (int i = 0; i < 16; ++i) { pos += sp[i]; neg += sn[i]; s2 += sc[i]; }
        unsigned long long nneg = (unsigned long long)NN * NN - s2;
        float ncomp = (float)((unsigned long long)NN + nneg);
        out[0] = (pos + neg) / ncomp;
    }
}

// ---------------------------------------------------------------------------
// ws layout (bytes):
//   up   @ 0        : 131072  (float2[16384]: {u, label})
//   vcp  @ 131072   : 131072  (float2[16384]: {vc, label})
//   ebf  @ 262144   : 2097152
//   posP @ 2359296  : 16384   (NPOSB floats)
//   negP @ 2375680  : 2048    (NBLK=512 floats)
//   total 2377728
// ---------------------------------------------------------------------------
extern "C" void kernel_launch(void* const* d_in, const int* in_sizes, int n_in,
                              void* d_out, int out_size, void* d_ws, size_t ws_size,
                              hipStream_t stream) {
    const float* emb = (const float*)d_in[0];
    const int* lab   = (const int*)d_in[1];
    const int* pidx  = (const int*)d_in[2];
    float* out = (float*)d_out;
    char* ws = (char*)d_ws;
    float2*         up   = (float2*)(ws);
    float2*         vcp  = (float2*)(ws + 131072);
    __hip_bfloat16* ebf  = (__hip_bfloat16*)(ws + 262144);
    float*          posP = (float*)(ws + 2359296);
    float*          negP = (float*)(ws + 2375680);

    norm_kernel<<<NPOSB, 256, 0, stream>>>(emb, pidx, lab, up, vcp, ebf, posP);
    pair_kernel<<<NBLK, 512, 0, stream>>>((const short*)ebf, up, vcp, negP);
    reduce_kernel<<<1, 1024, 0, stream>>>(posP, negP, lab, out);
}